// Round 1
// baseline (627.238 us; speedup 1.0000x reference)
//
#include <hip/hip_runtime.h>

#define N_NODES 50000
#define N_EDGES 800000
#define N_GRAPHS 64

// ---------------- utility: zero scratch counters ----------------
__global__ void zero_kernel(int* __restrict__ cnt, float* __restrict__ gsum) {
    int i = blockIdx.x * 256 + threadIdx.x;
    if (i < N_NODES) cnt[i] = 0;
    if (i < N_GRAPHS * 128) gsum[i] = 0.f;
}

// ---------------- CSR build ----------------
__global__ void hist_kernel(const int* __restrict__ dst, int* __restrict__ cnt) {
    int e = blockIdx.x * 256 + threadIdx.x;
    if (e < N_EDGES) atomicAdd(&cnt[dst[e]], 1);
}

__global__ __launch_bounds__(1024) void scan_kernel(const int* __restrict__ cnt,
                                                    int* __restrict__ rowptr,
                                                    int* __restrict__ head) {
    __shared__ int sd[1024];
    const int t = threadIdx.x;
    const int CH = 49;                       // 49*1024 = 50176 >= 50000
    int b = t * CH;
    int e = min(b + CH, N_NODES);
    int s = 0;
    for (int i = b; i < e; ++i) s += cnt[i];
    sd[t] = s;
    __syncthreads();
    // Hillis-Steele inclusive scan over 1024 partials
    for (int off = 1; off < 1024; off <<= 1) {
        int v = sd[t];
        int add = (t >= off) ? sd[t - off] : 0;
        __syncthreads();
        sd[t] = v + add;
        __syncthreads();
    }
    int run = (t > 0) ? sd[t - 1] : 0;       // exclusive prefix
    for (int i = b; i < e; ++i) {
        rowptr[i] = run;
        head[i]   = run;
        run += cnt[i];
    }
    if (t == 1023) rowptr[N_NODES] = sd[1023];
}

__global__ void scatter_kernel(const int* __restrict__ src, const int* __restrict__ dst,
                               int* __restrict__ head, int* __restrict__ csr) {
    int e = blockIdx.x * 256 + threadIdx.x;
    if (e < N_EDGES) {
        int p = atomicAdd(&head[dst[e]], 1);
        csr[p] = src[e];
    }
}

// ---------------- embedding gather ----------------
__global__ void embed_kernel(const int* __restrict__ x_idx, const float* __restrict__ table,
                             float* __restrict__ X) {
    int i = blockIdx.x * 256 + threadIdx.x;
    if (i >= N_NODES * 32) return;
    int n = i >> 5, kq = i & 31;
    ((float4*)X)[n * 32 + kq] = ((const float4*)table)[x_idx[n] * 32 + kq];
}

// ---------------- mean aggregation: one wave per node, lane = 2 feats ----------------
__global__ __launch_bounds__(256) void agg_kernel(const float* __restrict__ X,
                                                  const int* __restrict__ rowptr,
                                                  const int* __restrict__ csr,
                                                  float* __restrict__ AGG) {
    int wid  = (blockIdx.x * 256 + threadIdx.x) >> 6;   // node = global wave id
    int lane = threadIdx.x & 63;
    if (wid >= N_NODES) return;
    int beg = rowptr[wid], end = rowptr[wid + 1];
    const float2* Xf = (const float2*)X;
    float sx = 0.f, sy = 0.f;
    int i = beg;
    for (; i + 4 <= end; i += 4) {               // 4-deep to overlap gather latency
        int s0 = csr[i], s1 = csr[i + 1], s2 = csr[i + 2], s3 = csr[i + 3];
        float2 v0 = Xf[s0 * 64 + lane];
        float2 v1 = Xf[s1 * 64 + lane];
        float2 v2 = Xf[s2 * 64 + lane];
        float2 v3 = Xf[s3 * 64 + lane];
        sx += (v0.x + v1.x) + (v2.x + v3.x);
        sy += (v0.y + v1.y) + (v2.y + v3.y);
    }
    for (; i < end; ++i) {
        float2 v = Xf[csr[i] * 64 + lane];
        sx += v.x; sy += v.y;
    }
    float inv = 1.f / (float)max(end - beg, 1);
    float2 o; o.x = sx * inv; o.y = sy * inv;
    ((float2*)AGG)[wid * 64 + lane] = o;
}

// ---------------- fused SAGE linear: Y = relu(A1@W1^T + A2@W2^T + bias) ----------------
// block = 256 thr (4 waves). wave q owns cols [q*32, q*32+32); lane = row within 64-row
// group; 4 row-groups per thread -> 256 rows/block. W staged in 64KB LDS (two k-passes);
// all 64 lanes of a wave read the SAME LDS address -> broadcast, conflict-free.
__global__ __launch_bounds__(256, 1) void gemm_kernel(const float* __restrict__ A1,
                                                      const float* __restrict__ A2,
                                                      const float* __restrict__ W1,
                                                      const float* __restrict__ W2,
                                                      const float* __restrict__ bias,
                                                      float* __restrict__ Y) {
    __shared__ float4 w[4096];                  // one 128x128 f32 matrix = 64KB
    const int t    = threadIdx.x;
    const int lane = t & 63;
    const int q    = t >> 6;
    const int row0 = blockIdx.x * 256;

    float acc[4][32];
#pragma unroll
    for (int g = 0; g < 4; ++g)
#pragma unroll
        for (int c = 0; c < 32; ++c) acc[g][c] = 0.f;

#pragma unroll 1
    for (int pass = 0; pass < 2; ++pass) {
        const float4* gw = pass ? (const float4*)W2 : (const float4*)W1;
        const float*  A  = pass ? A2 : A1;
        __syncthreads();                         // previous pass done reading LDS
#pragma unroll
        for (int i = 0; i < 16; ++i) w[i * 256 + t] = gw[i * 256 + t];
        __syncthreads();

        for (int k0 = 0; k0 < 128; k0 += 4) {
            float4 a[4];
#pragma unroll
            for (int g = 0; g < 4; ++g) {
                int r = row0 + g * 64 + lane;
                a[g] = (r < N_NODES) ? *(const float4*)(A + r * 128 + k0)
                                     : make_float4(0.f, 0.f, 0.f, 0.f);
            }
#pragma unroll
            for (int c = 0; c < 32; ++c) {
                float4 wv = w[(q * 32 + c) * 32 + (k0 >> 2)];   // broadcast read
#pragma unroll
                for (int g = 0; g < 4; ++g) {
                    acc[g][c] += a[g].x * wv.x + a[g].y * wv.y +
                                 a[g].z * wv.z + a[g].w * wv.w;
                }
            }
        }
    }
    // epilogue: bias + relu, float4 stores
#pragma unroll
    for (int g = 0; g < 4; ++g) {
        int r = row0 + g * 64 + lane;
        if (r < N_NODES) {
#pragma unroll
            for (int c4 = 0; c4 < 8; ++c4) {
                int cg = q * 32 + c4 * 4;
                float4 bv = *(const float4*)(bias + cg);
                float4 o;
                o.x = fmaxf(acc[g][c4 * 4 + 0] + bv.x, 0.f);
                o.y = fmaxf(acc[g][c4 * 4 + 1] + bv.y, 0.f);
                o.z = fmaxf(acc[g][c4 * 4 + 2] + bv.z, 0.f);
                o.w = fmaxf(acc[g][c4 * 4 + 3] + bv.w, 0.f);
                *(float4*)(Y + r * 128 + cg) = o;
            }
        }
    }
}

// ---------------- global mean pool (batch sorted -> binary search bounds) ----------------
__global__ __launch_bounds__(128) void pool_kernel(const float* __restrict__ Y,
                                                   const int* __restrict__ batch,
                                                   float* __restrict__ gsum) {
    int g = blockIdx.x;     // graph
    int p = blockIdx.y;     // 4 row-range parts per graph
    int c = threadIdx.x;    // 128 feature columns
    __shared__ int se[2];
    if (c < 2) {
        int target = g + c;
        int lo = 0, hi = N_NODES;
        while (lo < hi) { int mid = (lo + hi) >> 1; if (batch[mid] < target) lo = mid + 1; else hi = mid; }
        se[c] = lo;
    }
    __syncthreads();
    int beg = se[0], end = se[1];
    int len = end - beg;
    int b = beg + (len * p) / 4;
    int e = beg + (len * (p + 1)) / 4;
    float s0 = 0.f, s1 = 0.f;
    int n = b;
    for (; n + 2 <= e; n += 2) { s0 += Y[n * 128 + c]; s1 += Y[(n + 1) * 128 + c]; }
    if (n < e) s0 += Y[n * 128 + c];
    atomicAdd(&gsum[g * 128 + c], s0 + s1);
}

// ---------------- classifier: out[g,j] = linb[j] + dot(gsum[g]/cnt_g, linW[j]) ----------------
__global__ void final_kernel(const float* __restrict__ gsum, const int* __restrict__ batch,
                             const float* __restrict__ linW, const float* __restrict__ linb,
                             float* __restrict__ out) {
    int t = blockIdx.x * 256 + threadIdx.x;
    if (t >= N_GRAPHS * 10) return;
    int g = t / 10, j = t % 10;
    int bnd[2];
    for (int c = 0; c < 2; ++c) {
        int target = g + c;
        int lo = 0, hi = N_NODES;
        while (lo < hi) { int mid = (lo + hi) >> 1; if (batch[mid] < target) lo = mid + 1; else hi = mid; }
        bnd[c] = lo;
    }
    float invc = 1.f / (float)max(bnd[1] - bnd[0], 1);
    float s = 0.f;
    for (int k = 0; k < 128; ++k) s += gsum[g * 128 + k] * linW[j * 128 + k];
    out[t] = linb[j] + s * invc;
}

extern "C" void kernel_launch(void* const* d_in, const int* in_sizes, int n_in,
                              void* d_out, int out_size, void* d_ws, size_t ws_size,
                              hipStream_t stream) {
    const int*   x_idx = (const int*)d_in[0];
    const int*   eidx  = (const int*)d_in[1];   // [2][N_EDGES]
    const int*   batch = (const int*)d_in[2];
    const float* table = (const float*)d_in[3];
    const float* Wl1   = (const float*)d_in[4];
    const float* bl1   = (const float*)d_in[5];
    const float* Wr1   = (const float*)d_in[6];
    const float* Wl2   = (const float*)d_in[7];
    const float* bl2   = (const float*)d_in[8];
    const float* Wr2   = (const float*)d_in[9];
    const float* linW  = (const float*)d_in[10];
    const float* linb  = (const float*)d_in[11];
    float*       out   = (float*)d_out;

    const int* src = eidx;
    const int* dst = eidx + N_EDGES;

    // workspace layout (floats then ints); total ~80.6 MB
    float* B0   = (float*)d_ws;                          // x0 / y2
    float* B1   = B0 + (size_t)N_NODES * 128;            // agg
    float* B2   = B1 + (size_t)N_NODES * 128;            // y1
    float* gsum = B2 + (size_t)N_NODES * 128;            // [64][128]
    int* cnt    = (int*)(gsum + N_GRAPHS * 128);
    int* rowptr = cnt + N_NODES;                         // N_NODES+1
    int* head   = rowptr + (N_NODES + 1);
    int* csr    = head + N_NODES;                        // N_EDGES

    zero_kernel   <<<dim3((N_NODES + 255) / 256), 256, 0, stream>>>(cnt, gsum);
    hist_kernel   <<<dim3((N_EDGES + 255) / 256), 256, 0, stream>>>(dst, cnt);
    scan_kernel   <<<1, 1024, 0, stream>>>(cnt, rowptr, head);
    scatter_kernel<<<dim3((N_EDGES + 255) / 256), 256, 0, stream>>>(src, dst, head, csr);
    embed_kernel  <<<dim3((N_NODES * 32 + 255) / 256), 256, 0, stream>>>(x_idx, table, B0);

    // layer 1
    agg_kernel <<<dim3(N_NODES * 64 / 256), 256, 0, stream>>>(B0, rowptr, csr, B1);
    gemm_kernel<<<dim3((N_NODES + 255) / 256), 256, 0, stream>>>(B1, B0, Wl1, Wr1, bl1, B2);
    // layer 2
    agg_kernel <<<dim3(N_NODES * 64 / 256), 256, 0, stream>>>(B2, rowptr, csr, B1);
    gemm_kernel<<<dim3((N_NODES + 255) / 256), 256, 0, stream>>>(B1, B2, Wl2, Wr2, bl2, B0);

    // pool + classify
    pool_kernel <<<dim3(N_GRAPHS, 4), 128, 0, stream>>>(B0, batch, gsum);
    final_kernel<<<3, 256, 0, stream>>>(gsum, batch, linW, linb, out);
}

// Round 2
// 356.710 us; speedup vs baseline: 1.7584x; 1.7584x over previous
//
#include <hip/hip_runtime.h>

#define N_NODES 50000
#define N_EDGES 800000
#define N_GRAPHS 64

typedef __bf16 bf16x8 __attribute__((ext_vector_type(8)));
typedef float f32x4 __attribute__((ext_vector_type(4)));

// ---- bf16 helpers (RN-even pack, exact unpack) ----
static __device__ __forceinline__ unsigned short f2bf(float f) {
    union { float f; unsigned u; } v; v.f = f;
    unsigned u = v.u;
    u += 0x7fffu + ((u >> 16) & 1u);          // round-to-nearest-even
    return (unsigned short)(u >> 16);
}
static __device__ __forceinline__ float bf2f(unsigned short h) {
    union { unsigned u; float f; } v; v.u = ((unsigned)h) << 16; return v.f;
}
static __device__ __forceinline__ float bflo(unsigned w) {
    union { unsigned u; float f; } v; v.u = w << 16; return v.f;
}
static __device__ __forceinline__ float bfhi(unsigned w) {
    union { unsigned u; float f; } v; v.u = w & 0xffff0000u; return v.f;
}
static __device__ __forceinline__ unsigned pack8_lo(float4 a, float4 b, int sel) {
    // helper unused; kept minimal
    return 0u;
}

// ---------------- utility: zero scratch counters ----------------
__global__ void zero_kernel(int* __restrict__ cnt, float* __restrict__ gsum) {
    int i = blockIdx.x * 256 + threadIdx.x;
    if (i < N_NODES) cnt[i] = 0;
    if (i < N_GRAPHS * 128) gsum[i] = 0.f;
}

// ---------------- CSR build ----------------
__global__ void hist_kernel(const int* __restrict__ dst, int* __restrict__ cnt) {
    int e = blockIdx.x * 256 + threadIdx.x;
    if (e < N_EDGES) atomicAdd(&cnt[dst[e]], 1);
}

__global__ __launch_bounds__(1024) void scan_kernel(const int* __restrict__ cnt,
                                                    int* __restrict__ rowptr,
                                                    int* __restrict__ head) {
    __shared__ int sd[1024];
    const int t = threadIdx.x;
    const int CH = 49;                       // 49*1024 = 50176 >= 50000
    int b = t * CH;
    int e = min(b + CH, N_NODES);
    int s = 0;
    for (int i = b; i < e; ++i) s += cnt[i];
    sd[t] = s;
    __syncthreads();
    for (int off = 1; off < 1024; off <<= 1) {
        int v = sd[t];
        int add = (t >= off) ? sd[t - off] : 0;
        __syncthreads();
        sd[t] = v + add;
        __syncthreads();
    }
    int run = (t > 0) ? sd[t - 1] : 0;       // exclusive prefix
    for (int i = b; i < e; ++i) {
        rowptr[i] = run;
        head[i]   = run;
        run += cnt[i];
    }
    if (t == 1023) rowptr[N_NODES] = sd[1023];
}

__global__ void scatter_kernel(const int* __restrict__ src, const int* __restrict__ dst,
                               int* __restrict__ head, int* __restrict__ csr) {
    int e = blockIdx.x * 256 + threadIdx.x;
    if (e < N_EDGES) {
        int p = atomicAdd(&head[dst[e]], 1);
        csr[p] = src[e];
    }
}

// ---------------- embedding gather -> bf16 ----------------
__global__ void embed_kernel(const int* __restrict__ x_idx, const float* __restrict__ table,
                             unsigned short* __restrict__ X) {
    int i = blockIdx.x * 256 + threadIdx.x;          // node*16 + chunk
    if (i >= N_NODES * 16) return;
    int n = i >> 4, c = i & 15;
    const float4* src = (const float4*)(table + (size_t)x_idx[n] * 128 + c * 8);
    float4 a = src[0], b = src[1];
    uint4 o;
    o.x = (unsigned)f2bf(a.x) | ((unsigned)f2bf(a.y) << 16);
    o.y = (unsigned)f2bf(a.z) | ((unsigned)f2bf(a.w) << 16);
    o.z = (unsigned)f2bf(b.x) | ((unsigned)f2bf(b.y) << 16);
    o.w = (unsigned)f2bf(b.z) | ((unsigned)f2bf(b.w) << 16);
    ((uint4*)X)[i] = o;
}

// ---------------- mean aggregation (bf16 in/out, fp32 accumulate) ----------------
// one wave per node; lane = 1 dword = 2 features; 256 B gathered per edge row
__global__ __launch_bounds__(256) void agg_kernel(const unsigned short* __restrict__ X,
                                                  const int* __restrict__ rowptr,
                                                  const int* __restrict__ csr,
                                                  unsigned short* __restrict__ AGG) {
    int wid  = (blockIdx.x * 256 + threadIdx.x) >> 6;
    int lane = threadIdx.x & 63;
    if (wid >= N_NODES) return;
    int beg = rowptr[wid], end = rowptr[wid + 1];
    const unsigned* Xw = (const unsigned*)X;
    float sx = 0.f, sy = 0.f;
    int i = beg;
    for (; i + 8 <= end; i += 8) {              // 8-deep to overlap gather latency
        unsigned v0 = Xw[(size_t)csr[i + 0] * 64 + lane];
        unsigned v1 = Xw[(size_t)csr[i + 1] * 64 + lane];
        unsigned v2 = Xw[(size_t)csr[i + 2] * 64 + lane];
        unsigned v3 = Xw[(size_t)csr[i + 3] * 64 + lane];
        unsigned v4 = Xw[(size_t)csr[i + 4] * 64 + lane];
        unsigned v5 = Xw[(size_t)csr[i + 5] * 64 + lane];
        unsigned v6 = Xw[(size_t)csr[i + 6] * 64 + lane];
        unsigned v7 = Xw[(size_t)csr[i + 7] * 64 + lane];
        sx += ((bflo(v0) + bflo(v1)) + (bflo(v2) + bflo(v3))) +
              ((bflo(v4) + bflo(v5)) + (bflo(v6) + bflo(v7)));
        sy += ((bfhi(v0) + bfhi(v1)) + (bfhi(v2) + bfhi(v3))) +
              ((bfhi(v4) + bfhi(v5)) + (bfhi(v6) + bfhi(v7)));
    }
    for (; i < end; ++i) {
        unsigned v = Xw[(size_t)csr[i] * 64 + lane];
        sx += bflo(v); sy += bfhi(v);
    }
    float inv = 1.f / (float)max(end - beg, 1);
    ((unsigned*)AGG)[(size_t)wid * 64 + lane] =
        (unsigned)f2bf(sx * inv) | ((unsigned)f2bf(sy * inv) << 16);
}

// ---------------- weight prep: fp32 [128][128] x4 -> bf16 fragment-ordered blobs ----------------
// frag index fidx = (m*4 + kk)*8 + tile ; slot = fidx*64 + lane (16B each)
// lane holds W[tile*16 + (lane&15)][kk*32 + (lane>>4)*8 .. +8]  (B-operand of mfma 16x16x32)
__global__ void prep_w_kernel(const float* __restrict__ Wl1, const float* __restrict__ Wr1,
                              const float* __restrict__ Wl2, const float* __restrict__ Wr2,
                              unsigned short* __restrict__ blob) {
    int s = blockIdx.x * 256 + threadIdx.x;          // 2 gemms * 4096 slots
    if (s >= 8192) return;
    int g = s >> 12;
    int sl = s & 4095;
    int fidx = sl >> 6, lane = sl & 63;
    int m = fidx >> 5, kk = (fidx >> 3) & 3, tile = fidx & 7;
    const float* W = g ? (m ? Wr2 : Wl2) : (m ? Wr1 : Wl1);
    int n  = tile * 16 + (lane & 15);
    int k0 = kk * 32 + (lane >> 4) * 8;
    const float4* src = (const float4*)(W + n * 128 + k0);
    float4 a = src[0], b = src[1];
    uint4 o;
    o.x = (unsigned)f2bf(a.x) | ((unsigned)f2bf(a.y) << 16);
    o.y = (unsigned)f2bf(a.z) | ((unsigned)f2bf(a.w) << 16);
    o.z = (unsigned)f2bf(b.x) | ((unsigned)f2bf(b.y) << 16);
    o.w = (unsigned)f2bf(b.z) | ((unsigned)f2bf(b.w) << 16);
    ((uint4*)blob)[s] = o;
}

// ---------------- fused SAGE linear via MFMA ----------------
// Y = relu(A0@Wl^T + A1@Wr^T + bias) as one K=256 bf16 GEMM, fp32 accumulate.
// block = 256 thr (4 waves); wave w owns rows [blk*128 + w*32, +32) x all 128 cols.
// Weights: 64KB fragment-ordered LDS, staged via linear global_load_lds (no conflicts).
__global__ __launch_bounds__(256) void gemm_kernel(const unsigned short* __restrict__ A0,
                                                   const unsigned short* __restrict__ A1,
                                                   const unsigned short* __restrict__ wblob,
                                                   const float* __restrict__ bias,
                                                   unsigned short* __restrict__ Y) {
    __shared__ char lds[65536];
    const int t = threadIdx.x, lane = t & 63, w = t >> 6;
    const int row0 = blockIdx.x * 128 + w * 32;

    // stage the 64KB blob -> LDS, linear copy, 16B per lane per issue
    {
        const char* src = (const char*)wblob + w * 16384 + lane * 16;
        char* dst = lds + w * 16384;
#pragma unroll
        for (int i = 0; i < 16; ++i) {
            __builtin_amdgcn_global_load_lds(
                (const __attribute__((address_space(1))) unsigned*)(src + i * 1024),
                (__attribute__((address_space(3))) unsigned*)(dst + i * 1024), 16, 0, 0);
        }
    }
    __syncthreads();   // drains vmcnt before barrier

    f32x4 acc[2][8];
#pragma unroll
    for (int rt = 0; rt < 2; ++rt)
#pragma unroll
        for (int tl = 0; tl < 8; ++tl) acc[rt][tl] = (f32x4){0.f, 0.f, 0.f, 0.f};

    int rA = min(row0 + (lane & 15),      N_NODES - 1);
    int rB = min(row0 + 16 + (lane & 15), N_NODES - 1);
    const int kl = (lane >> 4) * 8;

#pragma unroll
    for (int km = 0; km < 8; ++km) {             // km = m*4 + kk  (K=256 concat)
        const unsigned short* A = (km < 4) ? A0 : A1;
        int k0 = (km & 3) * 32 + kl;
        bf16x8 a0 = *(const bf16x8*)(A + (size_t)rA * 128 + k0);
        bf16x8 a1 = *(const bf16x8*)(A + (size_t)rB * 128 + k0);
        const char* bbase = lds + km * 8192 + lane * 16;
#pragma unroll
        for (int tile = 0; tile < 8; ++tile) {
            bf16x8 b = *(const bf16x8*)(bbase + tile * 1024);
            acc[0][tile] = __builtin_amdgcn_mfma_f32_16x16x32_bf16(a0, b, acc[0][tile], 0, 0, 0);
            acc[1][tile] = __builtin_amdgcn_mfma_f32_16x16x32_bf16(a1, b, acc[1][tile], 0, 0, 0);
        }
    }

    // epilogue: bias + relu + bf16 store. C/D: col=lane&15, row=(lane>>4)*4+j
    const int c     = lane & 15;
    const int rbase = (lane >> 4) * 4;
#pragma unroll
    for (int rt = 0; rt < 2; ++rt) {
#pragma unroll
        for (int tile = 0; tile < 8; ++tile) {
            int col = tile * 16 + c;
            float bv = bias[col];
#pragma unroll
            for (int j = 0; j < 4; ++j) {
                int r = row0 + rt * 16 + rbase + j;
                if (r < N_NODES)
                    Y[(size_t)r * 128 + col] = f2bf(fmaxf(acc[rt][tile][j] + bv, 0.f));
            }
        }
    }
}

// ---------------- global mean pool (bf16 in, fp32 out) ----------------
__global__ __launch_bounds__(128) void pool_kernel(const unsigned short* __restrict__ Y,
                                                   const int* __restrict__ batch,
                                                   float* __restrict__ gsum) {
    int g = blockIdx.x;
    int p = blockIdx.y;
    int c = threadIdx.x;
    __shared__ int se[2];
    if (c < 2) {
        int target = g + c;
        int lo = 0, hi = N_NODES;
        while (lo < hi) { int mid = (lo + hi) >> 1; if (batch[mid] < target) lo = mid + 1; else hi = mid; }
        se[c] = lo;
    }
    __syncthreads();
    int beg = se[0], end = se[1];
    int len = end - beg;
    int b = beg + (len * p) / 4;
    int e = beg + (len * (p + 1)) / 4;
    float s0 = 0.f, s1 = 0.f;
    int n = b;
    for (; n + 2 <= e; n += 2) {
        s0 += bf2f(Y[(size_t)n * 128 + c]);
        s1 += bf2f(Y[(size_t)(n + 1) * 128 + c]);
    }
    if (n < e) s0 += bf2f(Y[(size_t)n * 128 + c]);
    atomicAdd(&gsum[g * 128 + c], s0 + s1);
}

// ---------------- classifier ----------------
__global__ void final_kernel(const float* __restrict__ gsum, const int* __restrict__ batch,
                             const float* __restrict__ linW, const float* __restrict__ linb,
                             float* __restrict__ out) {
    int t = blockIdx.x * 256 + threadIdx.x;
    if (t >= N_GRAPHS * 10) return;
    int g = t / 10, j = t % 10;
    int bnd[2];
    for (int c = 0; c < 2; ++c) {
        int target = g + c;
        int lo = 0, hi = N_NODES;
        while (lo < hi) { int mid = (lo + hi) >> 1; if (batch[mid] < target) lo = mid + 1; else hi = mid; }
        bnd[c] = lo;
    }
    float invc = 1.f / (float)max(bnd[1] - bnd[0], 1);
    float s = 0.f;
    for (int k = 0; k < 128; ++k) s += gsum[g * 128 + k] * linW[j * 128 + k];
    out[t] = linb[j] + s * invc;
}

extern "C" void kernel_launch(void* const* d_in, const int* in_sizes, int n_in,
                              void* d_out, int out_size, void* d_ws, size_t ws_size,
                              hipStream_t stream) {
    const int*   x_idx = (const int*)d_in[0];
    const int*   eidx  = (const int*)d_in[1];   // [2][N_EDGES]
    const int*   batch = (const int*)d_in[2];
    const float* table = (const float*)d_in[3];
    const float* Wl1   = (const float*)d_in[4];
    const float* bl1   = (const float*)d_in[5];
    const float* Wr1   = (const float*)d_in[6];
    const float* Wl2   = (const float*)d_in[7];
    const float* bl2   = (const float*)d_in[8];
    const float* Wr2   = (const float*)d_in[9];
    const float* linW  = (const float*)d_in[10];
    const float* linb  = (const float*)d_in[11];
    float*       out   = (float*)d_out;

    const int* src = eidx;
    const int* dst = eidx + N_EDGES;

    // workspace layout: 3 bf16 feature buffers + weight blob + gsum + CSR ints (~42.5 MB)
    unsigned short* X    = (unsigned short*)d_ws;                 // x0 / y2
    unsigned short* AGG  = X   + (size_t)N_NODES * 128;           // agg
    unsigned short* Y1   = AGG + (size_t)N_NODES * 128;           // y1
    unsigned short* blob = Y1  + (size_t)N_NODES * 128;           // 2 x 64KB frag-ordered
    float* gsum = (float*)(blob + 65536);
    int* cnt    = (int*)(gsum + N_GRAPHS * 128);
    int* rowptr = cnt + N_NODES;                                  // N_NODES+1
    int* head   = rowptr + (N_NODES + 1);
    int* csr    = head + N_NODES;                                 // N_EDGES

    zero_kernel   <<<dim3((N_NODES + 255) / 256), 256, 0, stream>>>(cnt, gsum);
    hist_kernel   <<<dim3((N_EDGES + 255) / 256), 256, 0, stream>>>(dst, cnt);
    scan_kernel   <<<1, 1024, 0, stream>>>(cnt, rowptr, head);
    scatter_kernel<<<dim3((N_EDGES + 255) / 256), 256, 0, stream>>>(src, dst, head, csr);
    embed_kernel  <<<dim3((N_NODES * 16 + 255) / 256), 256, 0, stream>>>(x_idx, table, X);
    prep_w_kernel <<<32, 256, 0, stream>>>(Wl1, Wr1, Wl2, Wr2, blob);

    // layer 1
    agg_kernel <<<dim3(N_NODES * 64 / 256), 256, 0, stream>>>(X, rowptr, csr, AGG);
    gemm_kernel<<<dim3((N_NODES + 127) / 128), 256, 0, stream>>>(AGG, X, blob, bl1, Y1);
    // layer 2
    agg_kernel <<<dim3(N_NODES * 64 / 256), 256, 0, stream>>>(Y1, rowptr, csr, AGG);
    gemm_kernel<<<dim3((N_NODES + 127) / 128), 256, 0, stream>>>(AGG, Y1, blob + 32768, bl2, X);

    // pool + classify
    pool_kernel <<<dim3(N_GRAPHS, 4), 128, 0, stream>>>(X, batch, gsum);
    final_kernel<<<3, 256, 0, stream>>>(gsum, batch, linW, linb, out);
}

// Round 3
// 258.056 us; speedup vs baseline: 2.4306x; 1.3823x over previous
//
#include <hip/hip_runtime.h>

#define N_NODES 50000
#define N_EDGES 800000
#define N_GRAPHS 64
#define SCAN_BLOCKS 196              // 196*256 = 50176 >= N_NODES

typedef __bf16 bf16x8 __attribute__((ext_vector_type(8)));
typedef float f32x4 __attribute__((ext_vector_type(4)));

// ---- bf16 helpers (RN-even pack, exact unpack) ----
static __device__ __forceinline__ unsigned short f2bf(float f) {
    union { float f; unsigned u; } v; v.f = f;
    unsigned u = v.u;
    u += 0x7fffu + ((u >> 16) & 1u);          // round-to-nearest-even
    return (unsigned short)(u >> 16);
}
static __device__ __forceinline__ float bf2f(unsigned short h) {
    union { unsigned u; float f; } v; v.u = ((unsigned)h) << 16; return v.f;
}
static __device__ __forceinline__ float bflo(unsigned w) {
    union { unsigned u; float f; } v; v.u = w << 16; return v.f;
}
static __device__ __forceinline__ float bfhi(unsigned w) {
    union { unsigned u; float f; } v; v.u = w & 0xffff0000u; return v.f;
}

// ---------------- utility: zero scratch counters ----------------
__global__ void zero_kernel(int* __restrict__ cnt, float* __restrict__ gsum) {
    int i = blockIdx.x * 256 + threadIdx.x;
    if (i < N_NODES) cnt[i] = 0;
    if (i < N_GRAPHS * 128) gsum[i] = 0.f;
}

// ---------------- CSR build ----------------
__global__ void hist_kernel(const int* __restrict__ dst, int* __restrict__ cnt) {
    int e = blockIdx.x * 256 + threadIdx.x;
    if (e < N_EDGES) atomicAdd(&cnt[dst[e]], 1);
}

// ---- 3-phase parallel exclusive scan of cnt -> rowptr/head ----
__global__ __launch_bounds__(256) void blocksum_kernel(const int* __restrict__ cnt,
                                                       int* __restrict__ bsum) {
    int i = blockIdx.x * 256 + threadIdx.x;
    int v = (i < N_NODES) ? cnt[i] : 0;
#pragma unroll
    for (int off = 32; off > 0; off >>= 1) v += __shfl_down(v, off, 64);
    __shared__ int ws[4];
    if ((threadIdx.x & 63) == 0) ws[threadIdx.x >> 6] = v;
    __syncthreads();
    if (threadIdx.x == 0) bsum[blockIdx.x] = ws[0] + ws[1] + ws[2] + ws[3];
}

__global__ __launch_bounds__(256) void bscan_kernel(const int* __restrict__ bsum,
                                                    int* __restrict__ boff) {
    __shared__ int sd[256];
    int t = threadIdx.x;
    sd[t] = (t < SCAN_BLOCKS) ? bsum[t] : 0;
    __syncthreads();
    for (int off = 1; off < 256; off <<= 1) {
        int add = (t >= off) ? sd[t - off] : 0;
        __syncthreads();
        sd[t] += add;
        __syncthreads();
    }
    if (t < SCAN_BLOCKS) boff[t] = (t > 0) ? sd[t - 1] : 0;   // exclusive block offset
}

__global__ __launch_bounds__(256) void rowptr_kernel(const int* __restrict__ cnt,
                                                     const int* __restrict__ boff,
                                                     int* __restrict__ rowptr,
                                                     int* __restrict__ head) {
    __shared__ int sd[256];
    int t = threadIdx.x;
    int i = blockIdx.x * 256 + t;
    int v = (i < N_NODES) ? cnt[i] : 0;
    sd[t] = v;
    __syncthreads();
    for (int off = 1; off < 256; off <<= 1) {
        int add = (t >= off) ? sd[t - off] : 0;
        __syncthreads();
        sd[t] += add;
        __syncthreads();
    }
    int excl = sd[t] - v + boff[blockIdx.x];
    if (i < N_NODES) { rowptr[i] = excl; head[i] = excl; }
    if (i == N_NODES - 1) rowptr[N_NODES] = excl + v;
}

__global__ void scatter_kernel(const int* __restrict__ src, const int* __restrict__ dst,
                               int* __restrict__ head, int* __restrict__ csr) {
    int e = blockIdx.x * 256 + threadIdx.x;
    if (e < N_EDGES) {
        int p = atomicAdd(&head[dst[e]], 1);
        csr[p] = src[e];
    }
}

// ---------------- embedding gather -> bf16 ----------------
__global__ void embed_kernel(const int* __restrict__ x_idx, const float* __restrict__ table,
                             unsigned short* __restrict__ X) {
    int i = blockIdx.x * 256 + threadIdx.x;          // node*16 + chunk
    if (i >= N_NODES * 16) return;
    int n = i >> 4, c = i & 15;
    const float4* src = (const float4*)(table + (size_t)x_idx[n] * 128 + c * 8);
    float4 a = src[0], b = src[1];
    uint4 o;
    o.x = (unsigned)f2bf(a.x) | ((unsigned)f2bf(a.y) << 16);
    o.y = (unsigned)f2bf(a.z) | ((unsigned)f2bf(a.w) << 16);
    o.z = (unsigned)f2bf(b.x) | ((unsigned)f2bf(b.y) << 16);
    o.w = (unsigned)f2bf(b.z) | ((unsigned)f2bf(b.w) << 16);
    ((uint4*)X)[i] = o;
}

// ---------------- mean aggregation (bf16 in/out, fp32 accumulate) ----------------
// one wave per node; lane = 1 dword = 2 features; 256 B gathered per edge row
__global__ __launch_bounds__(256) void agg_kernel(const unsigned short* __restrict__ X,
                                                  const int* __restrict__ rowptr,
                                                  const int* __restrict__ csr,
                                                  unsigned short* __restrict__ AGG) {
    int wid  = (blockIdx.x * 256 + threadIdx.x) >> 6;
    int lane = threadIdx.x & 63;
    if (wid >= N_NODES) return;
    int beg = rowptr[wid], end = rowptr[wid + 1];
    const unsigned* Xw = (const unsigned*)X;
    float sx = 0.f, sy = 0.f;
    int i = beg;
    for (; i + 8 <= end; i += 8) {              // 8-deep to overlap gather latency
        unsigned v0 = Xw[(size_t)csr[i + 0] * 64 + lane];
        unsigned v1 = Xw[(size_t)csr[i + 1] * 64 + lane];
        unsigned v2 = Xw[(size_t)csr[i + 2] * 64 + lane];
        unsigned v3 = Xw[(size_t)csr[i + 3] * 64 + lane];
        unsigned v4 = Xw[(size_t)csr[i + 4] * 64 + lane];
        unsigned v5 = Xw[(size_t)csr[i + 5] * 64 + lane];
        unsigned v6 = Xw[(size_t)csr[i + 6] * 64 + lane];
        unsigned v7 = Xw[(size_t)csr[i + 7] * 64 + lane];
        sx += ((bflo(v0) + bflo(v1)) + (bflo(v2) + bflo(v3))) +
              ((bflo(v4) + bflo(v5)) + (bflo(v6) + bflo(v7)));
        sy += ((bfhi(v0) + bfhi(v1)) + (bfhi(v2) + bfhi(v3))) +
              ((bfhi(v4) + bfhi(v5)) + (bfhi(v6) + bfhi(v7)));
    }
    for (; i < end; ++i) {
        unsigned v = Xw[(size_t)csr[i] * 64 + lane];
        sx += bflo(v); sy += bfhi(v);
    }
    float inv = 1.f / (float)max(end - beg, 1);
    ((unsigned*)AGG)[(size_t)wid * 64 + lane] =
        (unsigned)f2bf(sx * inv) | ((unsigned)f2bf(sy * inv) << 16);
}

// ---------------- weight prep: fp32 [128][128] x4 -> bf16 fragment-ordered blobs ----------------
// frag index fidx = (m*4 + kk)*8 + tile ; slot = fidx*64 + lane (16B each)
// lane holds W[tile*16 + (lane&15)][kk*32 + (lane>>4)*8 .. +8]  (B-operand of mfma 16x16x32)
__global__ void prep_w_kernel(const float* __restrict__ Wl1, const float* __restrict__ Wr1,
                              const float* __restrict__ Wl2, const float* __restrict__ Wr2,
                              unsigned short* __restrict__ blob) {
    int s = blockIdx.x * 256 + threadIdx.x;          // 2 gemms * 4096 slots
    if (s >= 8192) return;
    int g = s >> 12;
    int sl = s & 4095;
    int fidx = sl >> 6, lane = sl & 63;
    int m = fidx >> 5, kk = (fidx >> 3) & 3, tile = fidx & 7;
    const float* W = g ? (m ? Wr2 : Wl2) : (m ? Wr1 : Wl1);
    int n  = tile * 16 + (lane & 15);
    int k0 = kk * 32 + (lane >> 4) * 8;
    const float4* src = (const float4*)(W + n * 128 + k0);
    float4 a = src[0], b = src[1];
    uint4 o;
    o.x = (unsigned)f2bf(a.x) | ((unsigned)f2bf(a.y) << 16);
    o.y = (unsigned)f2bf(a.z) | ((unsigned)f2bf(a.w) << 16);
    o.z = (unsigned)f2bf(b.x) | ((unsigned)f2bf(b.y) << 16);
    o.w = (unsigned)f2bf(b.z) | ((unsigned)f2bf(b.w) << 16);
    ((uint4*)blob)[s] = o;
}

// ---------------- fused SAGE linear via MFMA ----------------
// Y = relu(A0@Wl^T + A1@Wr^T + bias) as one K=256 bf16 GEMM, fp32 accumulate.
// block = 256 thr (4 waves); wave w owns rows [blk*128 + w*32, +32) x all 128 cols.
// Weights: 64KB fragment-ordered LDS, staged via linear global_load_lds (no conflicts).
__global__ __launch_bounds__(256) void gemm_kernel(const unsigned short* __restrict__ A0,
                                                   const unsigned short* __restrict__ A1,
                                                   const unsigned short* __restrict__ wblob,
                                                   const float* __restrict__ bias,
                                                   unsigned short* __restrict__ Y) {
    __shared__ char lds[65536];
    const int t = threadIdx.x, lane = t & 63, w = t >> 6;
    const int row0 = blockIdx.x * 128 + w * 32;

    // stage the 64KB blob -> LDS, linear copy, 16B per lane per issue
    {
        const char* src = (const char*)wblob + w * 16384 + lane * 16;
        char* dst = lds + w * 16384;
#pragma unroll
        for (int i = 0; i < 16; ++i) {
            __builtin_amdgcn_global_load_lds(
                (const __attribute__((address_space(1))) unsigned*)(src + i * 1024),
                (__attribute__((address_space(3))) unsigned*)(dst + i * 1024), 16, 0, 0);
        }
    }
    __syncthreads();   // drains vmcnt before barrier

    f32x4 acc[2][8];
#pragma unroll
    for (int rt = 0; rt < 2; ++rt)
#pragma unroll
        for (int tl = 0; tl < 8; ++tl) acc[rt][tl] = (f32x4){0.f, 0.f, 0.f, 0.f};

    int rA = min(row0 + (lane & 15),      N_NODES - 1);
    int rB = min(row0 + 16 + (lane & 15), N_NODES - 1);
    const int kl = (lane >> 4) * 8;

#pragma unroll
    for (int km = 0; km < 8; ++km) {             // km = m*4 + kk  (K=256 concat)
        const unsigned short* A = (km < 4) ? A0 : A1;
        int k0 = (km & 3) * 32 + kl;
        bf16x8 a0 = *(const bf16x8*)(A + (size_t)rA * 128 + k0);
        bf16x8 a1 = *(const bf16x8*)(A + (size_t)rB * 128 + k0);
        const char* bbase = lds + km * 8192 + lane * 16;
#pragma unroll
        for (int tile = 0; tile < 8; ++tile) {
            bf16x8 b = *(const bf16x8*)(bbase + tile * 1024);
            acc[0][tile] = __builtin_amdgcn_mfma_f32_16x16x32_bf16(a0, b, acc[0][tile], 0, 0, 0);
            acc[1][tile] = __builtin_amdgcn_mfma_f32_16x16x32_bf16(a1, b, acc[1][tile], 0, 0, 0);
        }
    }

    // epilogue: bias + relu + bf16 store. C/D: col=lane&15, row=(lane>>4)*4+j
    const int c     = lane & 15;
    const int rbase = (lane >> 4) * 4;
#pragma unroll
    for (int rt = 0; rt < 2; ++rt) {
#pragma unroll
        for (int tile = 0; tile < 8; ++tile) {
            int col = tile * 16 + c;
            float bv = bias[col];
#pragma unroll
            for (int j = 0; j < 4; ++j) {
                int r = row0 + rt * 16 + rbase + j;
                if (r < N_NODES)
                    Y[(size_t)r * 128 + col] = f2bf(fmaxf(acc[rt][tile][j] + bv, 0.f));
            }
        }
    }
}

// ---------------- global mean pool (bf16 in, fp32 out) ----------------
__global__ __launch_bounds__(128) void pool_kernel(const unsigned short* __restrict__ Y,
                                                   const int* __restrict__ batch,
                                                   float* __restrict__ gsum) {
    int g = blockIdx.x;
    int p = blockIdx.y;
    int c = threadIdx.x;
    __shared__ int se[2];
    if (c < 2) {
        int target = g + c;
        int lo = 0, hi = N_NODES;
        while (lo < hi) { int mid = (lo + hi) >> 1; if (batch[mid] < target) lo = mid + 1; else hi = mid; }
        se[c] = lo;
    }
    __syncthreads();
    int beg = se[0], end = se[1];
    int len = end - beg;
    int b = beg + (len * p) / 4;
    int e = beg + (len * (p + 1)) / 4;
    float s0 = 0.f, s1 = 0.f;
    int n = b;
    for (; n + 2 <= e; n += 2) {
        s0 += bf2f(Y[(size_t)n * 128 + c]);
        s1 += bf2f(Y[(size_t)(n + 1) * 128 + c]);
    }
    if (n < e) s0 += bf2f(Y[(size_t)n * 128 + c]);
    atomicAdd(&gsum[g * 128 + c], s0 + s1);
}

// ---------------- classifier ----------------
__global__ void final_kernel(const float* __restrict__ gsum, const int* __restrict__ batch,
                             const float* __restrict__ linW, const float* __restrict__ linb,
                             float* __restrict__ out) {
    int t = blockIdx.x * 256 + threadIdx.x;
    if (t >= N_GRAPHS * 10) return;
    int g = t / 10, j = t % 10;
    int bnd[2];
    for (int c = 0; c < 2; ++c) {
        int target = g + c;
        int lo = 0, hi = N_NODES;
        while (lo < hi) { int mid = (lo + hi) >> 1; if (batch[mid] < target) lo = mid + 1; else hi = mid; }
        bnd[c] = lo;
    }
    float invc = 1.f / (float)max(bnd[1] - bnd[0], 1);
    float s = 0.f;
    for (int k = 0; k < 128; ++k) s += gsum[g * 128 + k] * linW[j * 128 + k];
    out[t] = linb[j] + s * invc;
}

extern "C" void kernel_launch(void* const* d_in, const int* in_sizes, int n_in,
                              void* d_out, int out_size, void* d_ws, size_t ws_size,
                              hipStream_t stream) {
    const int*   x_idx = (const int*)d_in[0];
    const int*   eidx  = (const int*)d_in[1];   // [2][N_EDGES]
    const int*   batch = (const int*)d_in[2];
    const float* table = (const float*)d_in[3];
    const float* Wl1   = (const float*)d_in[4];
    const float* bl1   = (const float*)d_in[5];
    const float* Wr1   = (const float*)d_in[6];
    const float* Wl2   = (const float*)d_in[7];
    const float* bl2   = (const float*)d_in[8];
    const float* Wr2   = (const float*)d_in[9];
    const float* linW  = (const float*)d_in[10];
    const float* linb  = (const float*)d_in[11];
    float*       out   = (float*)d_out;

    const int* src = eidx;
    const int* dst = eidx + N_EDGES;

    // workspace layout: 3 bf16 feature buffers + weight blob + gsum + CSR ints (~42.5 MB)
    unsigned short* X    = (unsigned short*)d_ws;                 // x0 / y2
    unsigned short* AGG  = X   + (size_t)N_NODES * 128;           // agg
    unsigned short* Y1   = AGG + (size_t)N_NODES * 128;           // y1
    unsigned short* blob = Y1  + (size_t)N_NODES * 128;           // 2 x 64KB frag-ordered
    float* gsum = (float*)(blob + 65536);
    int* cnt    = (int*)(gsum + N_GRAPHS * 128);
    int* rowptr = cnt + N_NODES;                                  // N_NODES+1
    int* head   = rowptr + (N_NODES + 1);
    int* csr    = head + N_NODES;                                 // N_EDGES
    int* bsum   = csr + N_EDGES;                                  // SCAN_BLOCKS
    int* boff   = bsum + SCAN_BLOCKS;                             // SCAN_BLOCKS

    zero_kernel    <<<dim3((N_NODES + 255) / 256), 256, 0, stream>>>(cnt, gsum);
    hist_kernel    <<<dim3((N_EDGES + 255) / 256), 256, 0, stream>>>(dst, cnt);
    blocksum_kernel<<<SCAN_BLOCKS, 256, 0, stream>>>(cnt, bsum);
    bscan_kernel   <<<1, 256, 0, stream>>>(bsum, boff);
    rowptr_kernel  <<<SCAN_BLOCKS, 256, 0, stream>>>(cnt, boff, rowptr, head);
    scatter_kernel <<<dim3((N_EDGES + 255) / 256), 256, 0, stream>>>(src, dst, head, csr);
    embed_kernel   <<<dim3((N_NODES * 16 + 255) / 256), 256, 0, stream>>>(x_idx, table, X);
    prep_w_kernel  <<<32, 256, 0, stream>>>(Wl1, Wr1, Wl2, Wr2, blob);

    // layer 1
    agg_kernel <<<dim3(N_NODES * 64 / 256), 256, 0, stream>>>(X, rowptr, csr, AGG);
    gemm_kernel<<<dim3((N_NODES + 127) / 128), 256, 0, stream>>>(AGG, X, blob, bl1, Y1);
    // layer 2
    agg_kernel <<<dim3(N_NODES * 64 / 256), 256, 0, stream>>>(Y1, rowptr, csr, AGG);
    gemm_kernel<<<dim3((N_NODES + 127) / 128), 256, 0, stream>>>(AGG, Y1, blob + 32768, bl2, X);

    // pool + classify
    pool_kernel <<<dim3(N_GRAPHS, 4), 128, 0, stream>>>(X, batch, gsum);
    final_kernel<<<3, 256, 0, stream>>>(gsum, batch, linW, linb, out);
}

// Round 4
// 211.506 us; speedup vs baseline: 2.9656x; 1.2201x over previous
//
#include <hip/hip_runtime.h>

#define N_NODES 50000
#define N_EDGES 800000
#define N_GRAPHS 64
#define SCAN_BLOCKS 196              // 196*256 = 50176 >= N_NODES

// CSR build partitioning: zero device atomics
#define NCHUNK 32
#define CHUNK_E (N_EDGES / NCHUNK)   // 25000
#define NRANGE 4
#define RSZ (N_NODES / NRANGE)       // 12500 counters = 50KB LDS

typedef __bf16 bf16x8 __attribute__((ext_vector_type(8)));
typedef float f32x4 __attribute__((ext_vector_type(4)));

// ---- bf16 helpers (RN-even pack, exact unpack) ----
static __device__ __forceinline__ unsigned short f2bf(float f) {
    union { float f; unsigned u; } v; v.f = f;
    unsigned u = v.u;
    u += 0x7fffu + ((u >> 16) & 1u);          // round-to-nearest-even
    return (unsigned short)(u >> 16);
}
static __device__ __forceinline__ float bf2f(unsigned short h) {
    union { unsigned u; float f; } v; v.u = ((unsigned)h) << 16; return v.f;
}
static __device__ __forceinline__ float bflo(unsigned w) {
    union { unsigned u; float f; } v; v.u = w << 16; return v.f;
}
static __device__ __forceinline__ float bfhi(unsigned w) {
    union { unsigned u; float f; } v; v.u = w & 0xffff0000u; return v.f;
}

// ---------------- zero gsum (pool accumulator) ----------------
__global__ void zero_kernel(float* __restrict__ gsum) {
    int i = blockIdx.x * 256 + threadIdx.x;
    if (i < N_GRAPHS * 128) gsum[i] = 0.f;
}

// ---------------- CSR build, pass 1: per-(chunk,range) LDS histogram ----------------
__global__ __launch_bounds__(256) void histpart_kernel(const int* __restrict__ dst,
                                                       int* __restrict__ part) {
    __shared__ int h[RSZ];
    const int c = blockIdx.x >> 2;           // chunk
    const int r = blockIdx.x & 3;            // node range
    const int rbase = r * RSZ;
    for (int i = threadIdx.x; i < RSZ; i += 256) h[i] = 0;
    __syncthreads();
    const int4* d4 = (const int4*)(dst + c * CHUNK_E);
    for (int i = threadIdx.x; i < CHUNK_E / 4; i += 256) {
        int4 d = d4[i];
        unsigned a;
        a = (unsigned)(d.x - rbase); if (a < RSZ) atomicAdd(&h[a], 1);
        a = (unsigned)(d.y - rbase); if (a < RSZ) atomicAdd(&h[a], 1);
        a = (unsigned)(d.z - rbase); if (a < RSZ) atomicAdd(&h[a], 1);
        a = (unsigned)(d.w - rbase); if (a < RSZ) atomicAdd(&h[a], 1);
    }
    __syncthreads();
    int* p = part + (size_t)c * N_NODES + rbase;
    for (int i = threadIdx.x; i < RSZ; i += 256) p[i] = h[i];
}

// ---------------- pass 2a: cnt[n] = sum over chunks ----------------
__global__ void cnt_kernel(const int* __restrict__ part, int* __restrict__ cnt) {
    int n = blockIdx.x * 256 + threadIdx.x;
    if (n >= N_NODES) return;
    int s = 0;
#pragma unroll
    for (int c = 0; c < NCHUNK; ++c) s += part[(size_t)c * N_NODES + n];
    cnt[n] = s;
}

// ---- 3-phase parallel exclusive scan of cnt -> rowptr ----
__global__ __launch_bounds__(256) void blocksum_kernel(const int* __restrict__ cnt,
                                                       int* __restrict__ bsum) {
    int i = blockIdx.x * 256 + threadIdx.x;
    int v = (i < N_NODES) ? cnt[i] : 0;
#pragma unroll
    for (int off = 32; off > 0; off >>= 1) v += __shfl_down(v, off, 64);
    __shared__ int ws[4];
    if ((threadIdx.x & 63) == 0) ws[threadIdx.x >> 6] = v;
    __syncthreads();
    if (threadIdx.x == 0) bsum[blockIdx.x] = ws[0] + ws[1] + ws[2] + ws[3];
}

__global__ __launch_bounds__(256) void bscan_kernel(const int* __restrict__ bsum,
                                                    int* __restrict__ boff) {
    __shared__ int sd[256];
    int t = threadIdx.x;
    sd[t] = (t < SCAN_BLOCKS) ? bsum[t] : 0;
    __syncthreads();
    for (int off = 1; off < 256; off <<= 1) {
        int add = (t >= off) ? sd[t - off] : 0;
        __syncthreads();
        sd[t] += add;
        __syncthreads();
    }
    if (t < SCAN_BLOCKS) boff[t] = (t > 0) ? sd[t - 1] : 0;   // exclusive block offset
}

__global__ __launch_bounds__(256) void rowptr_kernel(const int* __restrict__ cnt,
                                                     const int* __restrict__ boff,
                                                     int* __restrict__ rowptr) {
    __shared__ int sd[256];
    int t = threadIdx.x;
    int i = blockIdx.x * 256 + t;
    int v = (i < N_NODES) ? cnt[i] : 0;
    sd[t] = v;
    __syncthreads();
    for (int off = 1; off < 256; off <<= 1) {
        int add = (t >= off) ? sd[t - off] : 0;
        __syncthreads();
        sd[t] += add;
        __syncthreads();
    }
    int excl = sd[t] - v + boff[blockIdx.x];
    if (i < N_NODES) rowptr[i] = excl;
    if (i == N_NODES - 1) rowptr[N_NODES] = excl + v;
}

// ---------------- pass 2b: per-chunk exclusive offsets ----------------
__global__ void off_kernel(const int* __restrict__ part, const int* __restrict__ rowptr,
                           int* __restrict__ off) {
    int n = blockIdx.x * 256 + threadIdx.x;
    if (n >= N_NODES) return;
    int run = rowptr[n];
#pragma unroll
    for (int c = 0; c < NCHUNK; ++c) {
        off[(size_t)c * N_NODES + n] = run;
        run += part[(size_t)c * N_NODES + n];
    }
}

// ---------------- pass 3: scatter, LDS position counters, no device atomics ----------------
// blockIdx = c*4 + r  =>  blockIdx%8 in {r, r+4}: each node-range's csr region is
// written from at most 2 XCDs -> lines accumulate in L2, near-full-line writeback.
__global__ __launch_bounds__(256) void scatter_kernel(const int* __restrict__ src,
                                                      const int* __restrict__ dst,
                                                      const int* __restrict__ off,
                                                      int* __restrict__ csr) {
    __shared__ int h[RSZ];
    const int c = blockIdx.x >> 2;
    const int r = blockIdx.x & 3;
    const int rbase = r * RSZ;
    const int* o = off + (size_t)c * N_NODES + rbase;
    for (int i = threadIdx.x; i < RSZ; i += 256) h[i] = o[i];
    __syncthreads();
    const int4* d4 = (const int4*)(dst + c * CHUNK_E);
    const int4* s4 = (const int4*)(src + c * CHUNK_E);
    for (int i = threadIdx.x; i < CHUNK_E / 4; i += 256) {
        int4 d = d4[i];
        int4 s = s4[i];
        unsigned a;
        a = (unsigned)(d.x - rbase); if (a < RSZ) csr[atomicAdd(&h[a], 1)] = s.x;
        a = (unsigned)(d.y - rbase); if (a < RSZ) csr[atomicAdd(&h[a], 1)] = s.y;
        a = (unsigned)(d.z - rbase); if (a < RSZ) csr[atomicAdd(&h[a], 1)] = s.z;
        a = (unsigned)(d.w - rbase); if (a < RSZ) csr[atomicAdd(&h[a], 1)] = s.w;
    }
}

// ---------------- embedding gather -> bf16 ----------------
__global__ void embed_kernel(const int* __restrict__ x_idx, const float* __restrict__ table,
                             unsigned short* __restrict__ X) {
    int i = blockIdx.x * 256 + threadIdx.x;          // node*16 + chunk
    if (i >= N_NODES * 16) return;
    int n = i >> 4, c = i & 15;
    const float4* src = (const float4*)(table + (size_t)x_idx[n] * 128 + c * 8);
    float4 a = src[0], b = src[1];
    uint4 o;
    o.x = (unsigned)f2bf(a.x) | ((unsigned)f2bf(a.y) << 16);
    o.y = (unsigned)f2bf(a.z) | ((unsigned)f2bf(a.w) << 16);
    o.z = (unsigned)f2bf(b.x) | ((unsigned)f2bf(b.y) << 16);
    o.w = (unsigned)f2bf(b.z) | ((unsigned)f2bf(b.w) << 16);
    ((uint4*)X)[i] = o;
}

// ---------------- mean aggregation (bf16 in/out, fp32 accumulate) ----------------
// one wave per node; lane = 1 dword = 2 features; 256 B gathered per edge row
__global__ __launch_bounds__(256) void agg_kernel(const unsigned short* __restrict__ X,
                                                  const int* __restrict__ rowptr,
                                                  const int* __restrict__ csr,
                                                  unsigned short* __restrict__ AGG) {
    int wid  = (blockIdx.x * 256 + threadIdx.x) >> 6;
    int lane = threadIdx.x & 63;
    if (wid >= N_NODES) return;
    int beg = rowptr[wid], end = rowptr[wid + 1];
    const unsigned* Xw = (const unsigned*)X;
    float sx = 0.f, sy = 0.f;
    int i = beg;
    for (; i + 8 <= end; i += 8) {              // 8-deep to overlap gather latency
        unsigned v0 = Xw[(size_t)csr[i + 0] * 64 + lane];
        unsigned v1 = Xw[(size_t)csr[i + 1] * 64 + lane];
        unsigned v2 = Xw[(size_t)csr[i + 2] * 64 + lane];
        unsigned v3 = Xw[(size_t)csr[i + 3] * 64 + lane];
        unsigned v4 = Xw[(size_t)csr[i + 4] * 64 + lane];
        unsigned v5 = Xw[(size_t)csr[i + 5] * 64 + lane];
        unsigned v6 = Xw[(size_t)csr[i + 6] * 64 + lane];
        unsigned v7 = Xw[(size_t)csr[i + 7] * 64 + lane];
        sx += ((bflo(v0) + bflo(v1)) + (bflo(v2) + bflo(v3))) +
              ((bflo(v4) + bflo(v5)) + (bflo(v6) + bflo(v7)));
        sy += ((bfhi(v0) + bfhi(v1)) + (bfhi(v2) + bfhi(v3))) +
              ((bfhi(v4) + bfhi(v5)) + (bfhi(v6) + bfhi(v7)));
    }
    for (; i < end; ++i) {
        unsigned v = Xw[(size_t)csr[i] * 64 + lane];
        sx += bflo(v); sy += bfhi(v);
    }
    float inv = 1.f / (float)max(end - beg, 1);
    ((unsigned*)AGG)[(size_t)wid * 64 + lane] =
        (unsigned)f2bf(sx * inv) | ((unsigned)f2bf(sy * inv) << 16);
}

// ---------------- weight prep: fp32 [128][128] x4 -> bf16 fragment-ordered blobs ----------------
// frag index fidx = (m*4 + kk)*8 + tile ; slot = fidx*64 + lane (16B each)
// lane holds W[tile*16 + (lane&15)][kk*32 + (lane>>4)*8 .. +8]  (B-operand of mfma 16x16x32)
__global__ void prep_w_kernel(const float* __restrict__ Wl1, const float* __restrict__ Wr1,
                              const float* __restrict__ Wl2, const float* __restrict__ Wr2,
                              unsigned short* __restrict__ blob) {
    int s = blockIdx.x * 256 + threadIdx.x;          // 2 gemms * 4096 slots
    if (s >= 8192) return;
    int g = s >> 12;
    int sl = s & 4095;
    int fidx = sl >> 6, lane = sl & 63;
    int m = fidx >> 5, kk = (fidx >> 3) & 3, tile = fidx & 7;
    const float* W = g ? (m ? Wr2 : Wl2) : (m ? Wr1 : Wl1);
    int n  = tile * 16 + (lane & 15);
    int k0 = kk * 32 + (lane >> 4) * 8;
    const float4* src = (const float4*)(W + n * 128 + k0);
    float4 a = src[0], b = src[1];
    uint4 o;
    o.x = (unsigned)f2bf(a.x) | ((unsigned)f2bf(a.y) << 16);
    o.y = (unsigned)f2bf(a.z) | ((unsigned)f2bf(a.w) << 16);
    o.z = (unsigned)f2bf(b.x) | ((unsigned)f2bf(b.y) << 16);
    o.w = (unsigned)f2bf(b.z) | ((unsigned)f2bf(b.w) << 16);
    ((uint4*)blob)[s] = o;
}

// ---------------- fused SAGE linear via MFMA ----------------
// Y = relu(A0@Wl^T + A1@Wr^T + bias) as one K=256 bf16 GEMM, fp32 accumulate.
// block = 256 thr (4 waves); wave w owns rows [blk*128 + w*32, +32) x all 128 cols.
// Weights: 64KB fragment-ordered LDS, staged via linear global_load_lds (no conflicts).
__global__ __launch_bounds__(256) void gemm_kernel(const unsigned short* __restrict__ A0,
                                                   const unsigned short* __restrict__ A1,
                                                   const unsigned short* __restrict__ wblob,
                                                   const float* __restrict__ bias,
                                                   unsigned short* __restrict__ Y) {
    __shared__ char lds[65536];
    const int t = threadIdx.x, lane = t & 63, w = t >> 6;
    const int row0 = blockIdx.x * 128 + w * 32;

    // stage the 64KB blob -> LDS, linear copy, 16B per lane per issue
    {
        const char* src = (const char*)wblob + w * 16384 + lane * 16;
        char* dst = lds + w * 16384;
#pragma unroll
        for (int i = 0; i < 16; ++i) {
            __builtin_amdgcn_global_load_lds(
                (const __attribute__((address_space(1))) unsigned*)(src + i * 1024),
                (__attribute__((address_space(3))) unsigned*)(dst + i * 1024), 16, 0, 0);
        }
    }
    __syncthreads();   // drains vmcnt before barrier

    f32x4 acc[2][8];
#pragma unroll
    for (int rt = 0; rt < 2; ++rt)
#pragma unroll
        for (int tl = 0; tl < 8; ++tl) acc[rt][tl] = (f32x4){0.f, 0.f, 0.f, 0.f};

    int rA = min(row0 + (lane & 15),      N_NODES - 1);
    int rB = min(row0 + 16 + (lane & 15), N_NODES - 1);
    const int kl = (lane >> 4) * 8;

#pragma unroll
    for (int km = 0; km < 8; ++km) {             // km = m*4 + kk  (K=256 concat)
        const unsigned short* A = (km < 4) ? A0 : A1;
        int k0 = (km & 3) * 32 + kl;
        bf16x8 a0 = *(const bf16x8*)(A + (size_t)rA * 128 + k0);
        bf16x8 a1 = *(const bf16x8*)(A + (size_t)rB * 128 + k0);
        const char* bbase = lds + km * 8192 + lane * 16;
#pragma unroll
        for (int tile = 0; tile < 8; ++tile) {
            bf16x8 b = *(const bf16x8*)(bbase + tile * 1024);
            acc[0][tile] = __builtin_amdgcn_mfma_f32_16x16x32_bf16(a0, b, acc[0][tile], 0, 0, 0);
            acc[1][tile] = __builtin_amdgcn_mfma_f32_16x16x32_bf16(a1, b, acc[1][tile], 0, 0, 0);
        }
    }

    // epilogue: bias + relu + bf16 store. C/D: col=lane&15, row=(lane>>4)*4+j
    const int c     = lane & 15;
    const int rbase = (lane >> 4) * 4;
#pragma unroll
    for (int rt = 0; rt < 2; ++rt) {
#pragma unroll
        for (int tile = 0; tile < 8; ++tile) {
            int col = tile * 16 + c;
            float bv = bias[col];
#pragma unroll
            for (int j = 0; j < 4; ++j) {
                int r = row0 + rt * 16 + rbase + j;
                if (r < N_NODES)
                    Y[(size_t)r * 128 + col] = f2bf(fmaxf(acc[rt][tile][j] + bv, 0.f));
            }
        }
    }
}

// ---------------- global mean pool (bf16 in, fp32 out) ----------------
__global__ __launch_bounds__(128) void pool_kernel(const unsigned short* __restrict__ Y,
                                                   const int* __restrict__ batch,
                                                   float* __restrict__ gsum) {
    int g = blockIdx.x;
    int p = blockIdx.y;
    int c = threadIdx.x;
    __shared__ int se[2];
    if (c < 2) {
        int target = g + c;
        int lo = 0, hi = N_NODES;
        while (lo < hi) { int mid = (lo + hi) >> 1; if (batch[mid] < target) lo = mid + 1; else hi = mid; }
        se[c] = lo;
    }
    __syncthreads();
    int beg = se[0], end = se[1];
    int len = end - beg;
    int b = beg + (len * p) / 4;
    int e = beg + (len * (p + 1)) / 4;
    float s0 = 0.f, s1 = 0.f;
    int n = b;
    for (; n + 2 <= e; n += 2) {
        s0 += bf2f(Y[(size_t)n * 128 + c]);
        s1 += bf2f(Y[(size_t)(n + 1) * 128 + c]);
    }
    if (n < e) s0 += bf2f(Y[(size_t)n * 128 + c]);
    atomicAdd(&gsum[g * 128 + c], s0 + s1);
}

// ---------------- classifier ----------------
__global__ void final_kernel(const float* __restrict__ gsum, const int* __restrict__ batch,
                             const float* __restrict__ linW, const float* __restrict__ linb,
                             float* __restrict__ out) {
    int t = blockIdx.x * 256 + threadIdx.x;
    if (t >= N_GRAPHS * 10) return;
    int g = t / 10, j = t % 10;
    int bnd[2];
    for (int c = 0; c < 2; ++c) {
        int target = g + c;
        int lo = 0, hi = N_NODES;
        while (lo < hi) { int mid = (lo + hi) >> 1; if (batch[mid] < target) lo = mid + 1; else hi = mid; }
        bnd[c] = lo;
    }
    float invc = 1.f / (float)max(bnd[1] - bnd[0], 1);
    float s = 0.f;
    for (int k = 0; k < 128; ++k) s += gsum[g * 128 + k] * linW[j * 128 + k];
    out[t] = linb[j] + s * invc;
}

extern "C" void kernel_launch(void* const* d_in, const int* in_sizes, int n_in,
                              void* d_out, int out_size, void* d_ws, size_t ws_size,
                              hipStream_t stream) {
    const int*   x_idx = (const int*)d_in[0];
    const int*   eidx  = (const int*)d_in[1];   // [2][N_EDGES]
    const int*   batch = (const int*)d_in[2];
    const float* table = (const float*)d_in[3];
    const float* Wl1   = (const float*)d_in[4];
    const float* bl1   = (const float*)d_in[5];
    const float* Wr1   = (const float*)d_in[6];
    const float* Wl2   = (const float*)d_in[7];
    const float* bl2   = (const float*)d_in[8];
    const float* Wr2   = (const float*)d_in[9];
    const float* linW  = (const float*)d_in[10];
    const float* linb  = (const float*)d_in[11];
    float*       out   = (float*)d_out;

    const int* src = eidx;
    const int* dst = eidx + N_EDGES;

    // workspace layout (~55 MB)
    unsigned short* X    = (unsigned short*)d_ws;                 // x0 / y2
    unsigned short* AGG  = X   + (size_t)N_NODES * 128;           // agg
    unsigned short* Y1   = AGG + (size_t)N_NODES * 128;           // y1
    unsigned short* blob = Y1  + (size_t)N_NODES * 128;           // 2 x 64KB frag-ordered
    float* gsum = (float*)(blob + 65536);
    int* cnt    = (int*)(gsum + N_GRAPHS * 128);
    int* rowptr = cnt + N_NODES;                                  // N_NODES+1
    int* csr    = rowptr + (N_NODES + 1);                         // N_EDGES
    int* bsum   = csr + N_EDGES;                                  // SCAN_BLOCKS
    int* boff   = bsum + SCAN_BLOCKS;                             // SCAN_BLOCKS
    int* part   = boff + SCAN_BLOCKS;                             // NCHUNK x N_NODES
    int* off    = part + (size_t)NCHUNK * N_NODES;                // NCHUNK x N_NODES

    // CSR build (no device atomics)
    histpart_kernel<<<NCHUNK * NRANGE, 256, 0, stream>>>(dst, part);
    cnt_kernel     <<<SCAN_BLOCKS, 256, 0, stream>>>(part, cnt);
    blocksum_kernel<<<SCAN_BLOCKS, 256, 0, stream>>>(cnt, bsum);
    bscan_kernel   <<<1, 256, 0, stream>>>(bsum, boff);
    rowptr_kernel  <<<SCAN_BLOCKS, 256, 0, stream>>>(cnt, boff, rowptr);
    off_kernel     <<<SCAN_BLOCKS, 256, 0, stream>>>(part, rowptr, off);
    scatter_kernel <<<NCHUNK * NRANGE, 256, 0, stream>>>(src, dst, off, csr);

    zero_kernel    <<<32, 256, 0, stream>>>(gsum);
    embed_kernel   <<<dim3((N_NODES * 16 + 255) / 256), 256, 0, stream>>>(x_idx, table, X);
    prep_w_kernel  <<<32, 256, 0, stream>>>(Wl1, Wr1, Wl2, Wr2, blob);

    // layer 1
    agg_kernel <<<dim3(N_NODES * 64 / 256), 256, 0, stream>>>(X, rowptr, csr, AGG);
    gemm_kernel<<<dim3((N_NODES + 127) / 128), 256, 0, stream>>>(AGG, X, blob, bl1, Y1);
    // layer 2
    agg_kernel <<<dim3(N_NODES * 64 / 256), 256, 0, stream>>>(Y1, rowptr, csr, AGG);
    gemm_kernel<<<dim3((N_NODES + 127) / 128), 256, 0, stream>>>(AGG, Y1, blob + 32768, bl2, X);

    // pool + classify
    pool_kernel <<<dim3(N_GRAPHS, 4), 128, 0, stream>>>(X, batch, gsum);
    final_kernel<<<3, 256, 0, stream>>>(gsum, batch, linW, linb, out);
}

// Round 5
// 171.610 us; speedup vs baseline: 3.6550x; 1.2325x over previous
//
#include <hip/hip_runtime.h>

#define N_NODES 50000
#define N_EDGES 800000
#define N_GRAPHS 64
#define SCAN_BLOCKS 196              // 196*256 = 50176 >= N_NODES

// CSR build partitioning: zero device atomics
#define NCHUNK 32
#define CHUNK_E (N_EDGES / NCHUNK)   // 25000
#define NRANGE 4
#define RSZ (N_NODES / NRANGE)       // 12500 counters = 50KB LDS

// fat k1 partition
#define K1_HIST (NCHUNK * NRANGE)    // 128 blocks
#define K1_EMBED (N_NODES * 16 / 256) // 3125 blocks
#define K1_PREP 32                   // 8192 threads: weight prep + gsum zero

typedef __bf16 bf16x8 __attribute__((ext_vector_type(8)));
typedef float f32x4 __attribute__((ext_vector_type(4)));

// ---- bf16 helpers (RN-even pack, exact unpack) ----
static __device__ __forceinline__ unsigned short f2bf(float f) {
    union { float f; unsigned u; } v; v.f = f;
    unsigned u = v.u;
    u += 0x7fffu + ((u >> 16) & 1u);          // round-to-nearest-even
    return (unsigned short)(u >> 16);
}
static __device__ __forceinline__ float bf2f(unsigned short h) {
    union { unsigned u; float f; } v; v.u = ((unsigned)h) << 16; return v.f;
}
static __device__ __forceinline__ float bflo(unsigned w) {
    union { unsigned u; float f; } v; v.u = w << 16; return v.f;
}
static __device__ __forceinline__ float bfhi(unsigned w) {
    union { unsigned u; float f; } v; v.u = w & 0xffff0000u; return v.f;
}

// ---------------- k1: histpart | embed | weight-prep + gsum zero ----------------
__global__ __launch_bounds__(256) void k1_kernel(const int* __restrict__ dst,
                                                 int* __restrict__ part,
                                                 const int* __restrict__ x_idx,
                                                 const float* __restrict__ table,
                                                 unsigned short* __restrict__ X,
                                                 const float* __restrict__ Wl1,
                                                 const float* __restrict__ Wr1,
                                                 const float* __restrict__ Wl2,
                                                 const float* __restrict__ Wr2,
                                                 unsigned short* __restrict__ blob,
                                                 float* __restrict__ gsum) {
    const int b = blockIdx.x;
    if (b < K1_HIST) {
        // ---- per-(chunk,range) LDS histogram of dst ----
        __shared__ int h[RSZ];
        const int c = b >> 2;            // chunk
        const int r = b & 3;             // node range
        const int rbase = r * RSZ;
        for (int i = threadIdx.x; i < RSZ; i += 256) h[i] = 0;
        __syncthreads();
        const int4* d4 = (const int4*)(dst + c * CHUNK_E);
        for (int i = threadIdx.x; i < CHUNK_E / 4; i += 256) {
            int4 d = d4[i];
            unsigned a;
            a = (unsigned)(d.x - rbase); if (a < RSZ) atomicAdd(&h[a], 1);
            a = (unsigned)(d.y - rbase); if (a < RSZ) atomicAdd(&h[a], 1);
            a = (unsigned)(d.z - rbase); if (a < RSZ) atomicAdd(&h[a], 1);
            a = (unsigned)(d.w - rbase); if (a < RSZ) atomicAdd(&h[a], 1);
        }
        __syncthreads();
        int* p = part + (size_t)c * N_NODES + rbase;
        for (int i = threadIdx.x; i < RSZ; i += 256) p[i] = h[i];
    } else if (b < K1_HIST + K1_EMBED) {
        // ---- embedding gather -> bf16 ----
        int i = (b - K1_HIST) * 256 + threadIdx.x;   // node*16 + chunk
        int n = i >> 4, cq = i & 15;
        const float4* src = (const float4*)(table + (size_t)x_idx[n] * 128 + cq * 8);
        float4 a = src[0], bb = src[1];
        uint4 o;
        o.x = (unsigned)f2bf(a.x)  | ((unsigned)f2bf(a.y)  << 16);
        o.y = (unsigned)f2bf(a.z)  | ((unsigned)f2bf(a.w)  << 16);
        o.z = (unsigned)f2bf(bb.x) | ((unsigned)f2bf(bb.y) << 16);
        o.w = (unsigned)f2bf(bb.z) | ((unsigned)f2bf(bb.w) << 16);
        ((uint4*)X)[i] = o;
    } else {
        // ---- weight prep (frag-ordered bf16 blob) + gsum zero ----
        int s = (b - K1_HIST - K1_EMBED) * 256 + threadIdx.x;   // [0, 8192)
        gsum[s] = 0.f;
        int g = s >> 12;
        int sl = s & 4095;
        int fidx = sl >> 6, lane = sl & 63;
        int m = fidx >> 5, kk = (fidx >> 3) & 3, tile = fidx & 7;
        const float* W = g ? (m ? Wr2 : Wl2) : (m ? Wr1 : Wl1);
        int n  = tile * 16 + (lane & 15);
        int k0 = kk * 32 + (lane >> 4) * 8;
        const float4* src = (const float4*)(W + n * 128 + k0);
        float4 a = src[0], bb = src[1];
        uint4 o;
        o.x = (unsigned)f2bf(a.x)  | ((unsigned)f2bf(a.y)  << 16);
        o.y = (unsigned)f2bf(a.z)  | ((unsigned)f2bf(a.w)  << 16);
        o.z = (unsigned)f2bf(bb.x) | ((unsigned)f2bf(bb.y) << 16);
        o.w = (unsigned)f2bf(bb.z) | ((unsigned)f2bf(bb.w) << 16);
        ((uint4*)blob)[s] = o;
    }
}

// ---------------- cnt + per-block sum (fused) ----------------
__global__ __launch_bounds__(256) void cntsum_kernel(const int* __restrict__ part,
                                                     int* __restrict__ cnt,
                                                     int* __restrict__ bsum) {
    int t = threadIdx.x;
    int n = blockIdx.x * 256 + t;
    int s = 0;
    if (n < N_NODES) {
#pragma unroll
        for (int c = 0; c < NCHUNK; ++c) s += part[(size_t)c * N_NODES + n];
        cnt[n] = s;
    }
#pragma unroll
    for (int off = 32; off > 0; off >>= 1) s += __shfl_down(s, off, 64);
    __shared__ int ws[4];
    if ((t & 63) == 0) ws[t >> 6] = s;
    __syncthreads();
    if (t == 0) bsum[blockIdx.x] = ws[0] + ws[1] + ws[2] + ws[3];
}

__global__ __launch_bounds__(256) void bscan_kernel(const int* __restrict__ bsum,
                                                    int* __restrict__ boff) {
    __shared__ int sd[256];
    int t = threadIdx.x;
    sd[t] = (t < SCAN_BLOCKS) ? bsum[t] : 0;
    __syncthreads();
    for (int off = 1; off < 256; off <<= 1) {
        int add = (t >= off) ? sd[t - off] : 0;
        __syncthreads();
        sd[t] += add;
        __syncthreads();
    }
    if (t < SCAN_BLOCKS) boff[t] = (t > 0) ? sd[t - 1] : 0;   // exclusive block offset
}

// ---------------- rowptr + per-chunk offsets (fused) ----------------
__global__ __launch_bounds__(256) void rowptroff_kernel(const int* __restrict__ cnt,
                                                        const int* __restrict__ boff,
                                                        const int* __restrict__ part,
                                                        int* __restrict__ rowptr,
                                                        int* __restrict__ off) {
    __shared__ int sd[256];
    int t = threadIdx.x;
    int i = blockIdx.x * 256 + t;
    int v = (i < N_NODES) ? cnt[i] : 0;
    sd[t] = v;
    __syncthreads();
    for (int o = 1; o < 256; o <<= 1) {
        int add = (t >= o) ? sd[t - o] : 0;
        __syncthreads();
        sd[t] += add;
        __syncthreads();
    }
    int excl = sd[t] - v + boff[blockIdx.x];
    if (i < N_NODES) {
        rowptr[i] = excl;
        if (i == N_NODES - 1) rowptr[N_NODES] = excl + v;
        int run = excl;
#pragma unroll
        for (int c = 0; c < NCHUNK; ++c) {
            off[(size_t)c * N_NODES + i] = run;
            run += part[(size_t)c * N_NODES + i];
        }
    }
}

// ---------------- scatter, LDS position counters, no device atomics ----------------
__global__ __launch_bounds__(256) void scatter_kernel(const int* __restrict__ src,
                                                      const int* __restrict__ dst,
                                                      const int* __restrict__ off,
                                                      int* __restrict__ csr) {
    __shared__ int h[RSZ];
    const int c = blockIdx.x >> 2;
    const int r = blockIdx.x & 3;
    const int rbase = r * RSZ;
    const int* o = off + (size_t)c * N_NODES + rbase;
    for (int i = threadIdx.x; i < RSZ; i += 256) h[i] = o[i];
    __syncthreads();
    const int4* d4 = (const int4*)(dst + c * CHUNK_E);
    const int4* s4 = (const int4*)(src + c * CHUNK_E);
    for (int i = threadIdx.x; i < CHUNK_E / 4; i += 256) {
        int4 d = d4[i];
        int4 s = s4[i];
        unsigned a;
        a = (unsigned)(d.x - rbase); if (a < RSZ) csr[atomicAdd(&h[a], 1)] = s.x;
        a = (unsigned)(d.y - rbase); if (a < RSZ) csr[atomicAdd(&h[a], 1)] = s.y;
        a = (unsigned)(d.z - rbase); if (a < RSZ) csr[atomicAdd(&h[a], 1)] = s.z;
        a = (unsigned)(d.w - rbase); if (a < RSZ) csr[atomicAdd(&h[a], 1)] = s.w;
    }
}

// ---------------- mean aggregation (bf16 in/out, fp32 accumulate) ----------------
__global__ __launch_bounds__(256) void agg_kernel(const unsigned short* __restrict__ X,
                                                  const int* __restrict__ rowptr,
                                                  const int* __restrict__ csr,
                                                  unsigned short* __restrict__ AGG) {
    int wid  = (blockIdx.x * 256 + threadIdx.x) >> 6;
    int lane = threadIdx.x & 63;
    if (wid >= N_NODES) return;
    int beg = rowptr[wid], end = rowptr[wid + 1];
    const unsigned* Xw = (const unsigned*)X;
    float sx = 0.f, sy = 0.f;
    int i = beg;
    for (; i + 8 <= end; i += 8) {              // 8-deep to overlap gather latency
        unsigned v0 = Xw[(size_t)csr[i + 0] * 64 + lane];
        unsigned v1 = Xw[(size_t)csr[i + 1] * 64 + lane];
        unsigned v2 = Xw[(size_t)csr[i + 2] * 64 + lane];
        unsigned v3 = Xw[(size_t)csr[i + 3] * 64 + lane];
        unsigned v4 = Xw[(size_t)csr[i + 4] * 64 + lane];
        unsigned v5 = Xw[(size_t)csr[i + 5] * 64 + lane];
        unsigned v6 = Xw[(size_t)csr[i + 6] * 64 + lane];
        unsigned v7 = Xw[(size_t)csr[i + 7] * 64 + lane];
        sx += ((bflo(v0) + bflo(v1)) + (bflo(v2) + bflo(v3))) +
              ((bflo(v4) + bflo(v5)) + (bflo(v6) + bflo(v7)));
        sy += ((bfhi(v0) + bfhi(v1)) + (bfhi(v2) + bfhi(v3))) +
              ((bfhi(v4) + bfhi(v5)) + (bfhi(v6) + bfhi(v7)));
    }
    for (; i < end; ++i) {
        unsigned v = Xw[(size_t)csr[i] * 64 + lane];
        sx += bflo(v); sy += bfhi(v);
    }
    float inv = 1.f / (float)max(end - beg, 1);
    ((unsigned*)AGG)[(size_t)wid * 64 + lane] =
        (unsigned)f2bf(sx * inv) | ((unsigned)f2bf(sy * inv) << 16);
}

// ---------------- fused SAGE linear via MFMA (layer 1: writes Y) ----------------
__global__ __launch_bounds__(256) void gemm_kernel(const unsigned short* __restrict__ A0,
                                                   const unsigned short* __restrict__ A1,
                                                   const unsigned short* __restrict__ wblob,
                                                   const float* __restrict__ bias,
                                                   unsigned short* __restrict__ Y) {
    __shared__ char lds[65536];
    const int t = threadIdx.x, lane = t & 63, w = t >> 6;
    const int row0 = blockIdx.x * 128 + w * 32;

    {
        const char* src = (const char*)wblob + w * 16384 + lane * 16;
        char* dst = lds + w * 16384;
#pragma unroll
        for (int i = 0; i < 16; ++i) {
            __builtin_amdgcn_global_load_lds(
                (const __attribute__((address_space(1))) unsigned*)(src + i * 1024),
                (__attribute__((address_space(3))) unsigned*)(dst + i * 1024), 16, 0, 0);
        }
    }
    __syncthreads();

    f32x4 acc[2][8];
#pragma unroll
    for (int rt = 0; rt < 2; ++rt)
#pragma unroll
        for (int tl = 0; tl < 8; ++tl) acc[rt][tl] = (f32x4){0.f, 0.f, 0.f, 0.f};

    int rA = min(row0 + (lane & 15),      N_NODES - 1);
    int rB = min(row0 + 16 + (lane & 15), N_NODES - 1);
    const int kl = (lane >> 4) * 8;

#pragma unroll
    for (int km = 0; km < 8; ++km) {
        const unsigned short* A = (km < 4) ? A0 : A1;
        int k0 = (km & 3) * 32 + kl;
        bf16x8 a0 = *(const bf16x8*)(A + (size_t)rA * 128 + k0);
        bf16x8 a1 = *(const bf16x8*)(A + (size_t)rB * 128 + k0);
        const char* bbase = lds + km * 8192 + lane * 16;
#pragma unroll
        for (int tile = 0; tile < 8; ++tile) {
            bf16x8 b = *(const bf16x8*)(bbase + tile * 1024);
            acc[0][tile] = __builtin_amdgcn_mfma_f32_16x16x32_bf16(a0, b, acc[0][tile], 0, 0, 0);
            acc[1][tile] = __builtin_amdgcn_mfma_f32_16x16x32_bf16(a1, b, acc[1][tile], 0, 0, 0);
        }
    }

    const int c     = lane & 15;
    const int rbase = (lane >> 4) * 4;
#pragma unroll
    for (int rt = 0; rt < 2; ++rt) {
#pragma unroll
        for (int tile = 0; tile < 8; ++tile) {
            int col = tile * 16 + c;
            float bv = bias[col];
#pragma unroll
            for (int j = 0; j < 4; ++j) {
                int r = row0 + rt * 16 + rbase + j;
                if (r < N_NODES)
                    Y[(size_t)r * 128 + col] = f2bf(fmaxf(acc[rt][tile][j] + bv, 0.f));
            }
        }
    }
}

// ---------------- layer-2 GEMM with fused mean-pool (no y2 write) ----------------
__global__ __launch_bounds__(256) void gemm_pool_kernel(const unsigned short* __restrict__ A0,
                                                        const unsigned short* __restrict__ A1,
                                                        const unsigned short* __restrict__ wblob,
                                                        const float* __restrict__ bias,
                                                        const int* __restrict__ batch,
                                                        float* __restrict__ gsum) {
    __shared__ char lds[65536];
    const int t = threadIdx.x, lane = t & 63, w = t >> 6;
    const int brow0 = blockIdx.x * 128;
    const int row0  = brow0 + w * 32;

    {
        const char* src = (const char*)wblob + w * 16384 + lane * 16;
        char* dst = lds + w * 16384;
#pragma unroll
        for (int i = 0; i < 16; ++i) {
            __builtin_amdgcn_global_load_lds(
                (const __attribute__((address_space(1))) unsigned*)(src + i * 1024),
                (__attribute__((address_space(3))) unsigned*)(dst + i * 1024), 16, 0, 0);
        }
    }
    __syncthreads();

    f32x4 acc[2][8];
#pragma unroll
    for (int rt = 0; rt < 2; ++rt)
#pragma unroll
        for (int tl = 0; tl < 8; ++tl) acc[rt][tl] = (f32x4){0.f, 0.f, 0.f, 0.f};

    int rA = min(row0 + (lane & 15),      N_NODES - 1);
    int rB = min(row0 + 16 + (lane & 15), N_NODES - 1);
    const int kl = (lane >> 4) * 8;

#pragma unroll
    for (int km = 0; km < 8; ++km) {
        const unsigned short* A = (km < 4) ? A0 : A1;
        int k0 = (km & 3) * 32 + kl;
        bf16x8 a0 = *(const bf16x8*)(A + (size_t)rA * 128 + k0);
        bf16x8 a1 = *(const bf16x8*)(A + (size_t)rB * 128 + k0);
        const char* bbase = lds + km * 8192 + lane * 16;
#pragma unroll
        for (int tile = 0; tile < 8; ++tile) {
            bf16x8 b = *(const bf16x8*)(bbase + tile * 1024);
            acc[0][tile] = __builtin_amdgcn_mfma_f32_16x16x32_bf16(a0, b, acc[0][tile], 0, 0, 0);
            acc[1][tile] = __builtin_amdgcn_mfma_f32_16x16x32_bf16(a1, b, acc[1][tile], 0, 0, 0);
        }
    }

    // epilogue: relu(acc+bias) -> reuse weight LDS as 128x128 f32 tile
    __syncthreads();                       // all waves done reading weights
    float* ftile = (float*)lds;
    const int c     = lane & 15;
    const int rbase = (lane >> 4) * 4;
#pragma unroll
    for (int rt = 0; rt < 2; ++rt) {
#pragma unroll
        for (int tile = 0; tile < 8; ++tile) {
            int col = tile * 16 + c;
            float bv = bias[col];
#pragma unroll
            for (int j = 0; j < 4; ++j) {
                int lr = w * 32 + rt * 16 + rbase + j;
                ftile[lr * 128 + col] = fmaxf(acc[rt][tile][j] + bv, 0.f);
            }
        }
    }
    __syncthreads();

    // per-graph column partial sums (batch sorted): thread = (col, row-half)
    const int col  = t & 127;
    const int half = t >> 7;
    float s = 0.f;
    int curg = -1;
    for (int rr = 0; rr < 64; ++rr) {
        int r = brow0 + half * 64 + rr;
        if (r >= N_NODES) break;
        int g = batch[r];
        if (g != curg) {
            if (curg >= 0) atomicAdd(&gsum[curg * 128 + col], s);
            curg = g; s = 0.f;
        }
        s += ftile[(half * 64 + rr) * 128 + col];
    }
    if (curg >= 0) atomicAdd(&gsum[curg * 128 + col], s);
}

// ---------------- classifier ----------------
__global__ void final_kernel(const float* __restrict__ gsum, const int* __restrict__ batch,
                             const float* __restrict__ linW, const float* __restrict__ linb,
                             float* __restrict__ out) {
    int t = blockIdx.x * 256 + threadIdx.x;
    if (t >= N_GRAPHS * 10) return;
    int g = t / 10, j = t % 10;
    int bnd[2];
    for (int c = 0; c < 2; ++c) {
        int target = g + c;
        int lo = 0, hi = N_NODES;
        while (lo < hi) { int mid = (lo + hi) >> 1; if (batch[mid] < target) lo = mid + 1; else hi = mid; }
        bnd[c] = lo;
    }
    float invc = 1.f / (float)max(bnd[1] - bnd[0], 1);
    float s = 0.f;
    for (int k = 0; k < 128; ++k) s += gsum[g * 128 + k] * linW[j * 128 + k];
    out[t] = linb[j] + s * invc;
}

extern "C" void kernel_launch(void* const* d_in, const int* in_sizes, int n_in,
                              void* d_out, int out_size, void* d_ws, size_t ws_size,
                              hipStream_t stream) {
    const int*   x_idx = (const int*)d_in[0];
    const int*   eidx  = (const int*)d_in[1];   // [2][N_EDGES]
    const int*   batch = (const int*)d_in[2];
    const float* table = (const float*)d_in[3];
    const float* Wl1   = (const float*)d_in[4];
    const float* bl1   = (const float*)d_in[5];
    const float* Wr1   = (const float*)d_in[6];
    const float* Wl2   = (const float*)d_in[7];
    const float* bl2   = (const float*)d_in[8];
    const float* Wr2   = (const float*)d_in[9];
    const float* linW  = (const float*)d_in[10];
    const float* linb  = (const float*)d_in[11];
    float*       out   = (float*)d_out;

    const int* src = eidx;
    const int* dst = eidx + N_EDGES;

    // workspace layout (~55 MB)
    unsigned short* X    = (unsigned short*)d_ws;                 // x0
    unsigned short* AGG  = X   + (size_t)N_NODES * 128;           // agg
    unsigned short* Y1   = AGG + (size_t)N_NODES * 128;           // y1
    unsigned short* blob = Y1  + (size_t)N_NODES * 128;           // 2 x 64KB frag-ordered
    float* gsum = (float*)(blob + 65536);
    int* cnt    = (int*)(gsum + N_GRAPHS * 128);
    int* rowptr = cnt + N_NODES;                                  // N_NODES+1
    int* csr    = rowptr + (N_NODES + 1);                         // N_EDGES
    int* bsum   = csr + N_EDGES;                                  // SCAN_BLOCKS
    int* boff   = bsum + SCAN_BLOCKS;                             // SCAN_BLOCKS
    int* part   = boff + SCAN_BLOCKS;                             // NCHUNK x N_NODES
    int* off    = part + (size_t)NCHUNK * N_NODES;                // NCHUNK x N_NODES

    // k1: histogram | embed | weight prep + gsum zero (one launch)
    k1_kernel<<<K1_HIST + K1_EMBED + K1_PREP, 256, 0, stream>>>(
        dst, part, x_idx, table, X, Wl1, Wr1, Wl2, Wr2, blob, gsum);
    // scan chain (3 launches)
    cntsum_kernel   <<<SCAN_BLOCKS, 256, 0, stream>>>(part, cnt, bsum);
    bscan_kernel    <<<1, 256, 0, stream>>>(bsum, boff);
    rowptroff_kernel<<<SCAN_BLOCKS, 256, 0, stream>>>(cnt, boff, part, rowptr, off);
    scatter_kernel  <<<NCHUNK * NRANGE, 256, 0, stream>>>(src, dst, off, csr);

    // layer 1
    agg_kernel <<<dim3(N_NODES * 64 / 256), 256, 0, stream>>>(X, rowptr, csr, AGG);
    gemm_kernel<<<dim3((N_NODES + 127) / 128), 256, 0, stream>>>(AGG, X, blob, bl1, Y1);
    // layer 2 (+ fused mean pool)
    agg_kernel      <<<dim3(N_NODES * 64 / 256), 256, 0, stream>>>(Y1, rowptr, csr, AGG);
    gemm_pool_kernel<<<dim3((N_NODES + 127) / 128), 256, 0, stream>>>(AGG, Y1, blob + 32768, bl2, batch, gsum);

    final_kernel<<<3, 256, 0, stream>>>(gsum, batch, linW, linb, out);
}